// Round 2
// baseline (822.173 us; speedup 1.0000x reference)
//
#include <hip/hip_runtime.h>

#define NSEQ 256
#define NRES 1024
#define CM   256
#define CC   32
#define CZ   128
#define EPS  1e-5f
#define SROW (NRES * CM)   // stride between s-rows of x for fixed r
#define MCH  32            // m-chunk size (floats)
#define XPAD 36            // padded row stride for x chunk (floats)

typedef float f4v __attribute__((ext_vector_type(4)));

// ===================== Kernel S: precompute wt[m][c], K1, K2 =====================
// wt[m][c] = nw[m] * w_ab[c][m]  (256x32, 32 KB, row-contiguous in c so the
// main kernel can scalar-load 8-float c-slices). K1[c] = sum_m wt[m][c];
// K2[c] = sum_m nb[m]*w_ab[c][m] + b_ab[c].
__global__ void opm_setup(const float* __restrict__ nw,
                          const float* __restrict__ nb,
                          const float* __restrict__ w_ab,
                          const float* __restrict__ b_ab,
                          float* __restrict__ wt_g,
                          float* __restrict__ k12)
{
    __shared__ float wls[CM * CC];
    const int t = threadIdx.x;          // 256 threads, t == m
    const float nwm = nw[t];
    #pragma unroll
    for (int c = 0; c < CC; ++c)
        wls[t * CC + c] = nwm * w_ab[c * CM + t];
    __syncthreads();
    for (int i = t; i < CM * CC; i += 256) wt_g[i] = wls[i];
    if (t < CC) {
        float k1 = 0.f, k2 = 0.f;
        for (int m = 0; m < CM; ++m) {
            k1 += wls[m * CC + t];
            k2 = fmaf(nb[m], w_ab[t * CM + m], k2);
        }
        k12[t]      = k1;
        k12[CC + t] = k2 + b_ab[t];
    }
}

// ===================== Kernel A: compute pre[r][z] =====================
// One block per residue r. 256 threads = 4 waves, 3 blocks/CU (43 KB LDS).
//  G-phase: wave w owns cols 8w..8w+7; lane owns rows lane+64j (j=0..3).
//    x from LDS (4 ds_read_b128 / mm-step), w via wave-uniform SCALAR loads
//    from the precomputed wt_g (s_load_dwordx8, off the LDS pipe).
//  Stats from prefetch registers during staging; shfl-reduce over the 8
//    c-lanes; published via small LDS arrays.
//  P2: a[s][c] = rstd*(G - mu*K1) + K2, stored to xt with XOR-swizzled
//    float4 slots (slot ^= s&7) -> conflict-free writes AND reads.
//  P3: o = A^T A / NSEQ, 4-way split-K over s, 4x4 tile per thread,
//    partials reduced through the (now free) xt region.
//  P4: pre[z] = o . w_out[z] + b_out[z] -> global workspace.
__launch_bounds__(256, 3)
__global__ void opm_compute(const float* __restrict__ msa,
                            const float* __restrict__ wt_g,
                            const float* __restrict__ k12,
                            const float* __restrict__ w_out,
                            const float* __restrict__ b_out,
                            float* __restrict__ pre_out)
{
    __shared__ float xt[NSEQ * XPAD];    // 36 KB: x chunk [s][36]; then a[s][32]; then o partials
    __shared__ float o_lds[CC * CC];     // 4 KB
    __shared__ float mu_s[NSEQ];         // 1 KB
    __shared__ float rs_s[NSEQ];         // 1 KB
    __shared__ float pre_part[2 * CZ];   // 1 KB

    const int tid  = threadIdx.x;
    const int r    = blockIdx.x;
    const int lane = tid & 63;
    const int wave = tid >> 6;                                   // 0..3
    const int cw   = __builtin_amdgcn_readfirstlane(wave << 3);  // uniform col base

    // staging identity
    const int sc = tid & 7;                 // float4 slot within chunk
    const int sg = tid >> 3;                // 0..31 staging row group
    const float* xr = msa + (size_t)r * CM;

    float G[4][8];
    #pragma unroll
    for (int j = 0; j < 4; ++j)
        #pragma unroll
        for (int c = 0; c < 8; ++c) G[j][c] = 0.f;

    float psum[8], pssq[8];
    #pragma unroll
    for (int k = 0; k < 8; ++k) { psum[k] = 0.f; pssq[k] = 0.f; }

    // prologue: prefetch chunk 0
    float4 pf[8];
    #pragma unroll
    for (int k = 0; k < 8; ++k)
        pf[k] = *(const float4*)(xr + (size_t)(sg + (k << 5)) * SROW + (sc << 2));

    for (int mb = 0; mb < CM; mb += MCH) {
        __syncthreads();   // previous chunk's readers done
        #pragma unroll
        for (int k = 0; k < 8; ++k) {
            *(float4*)&xt[(sg + (k << 5)) * XPAD + (sc << 2)] = pf[k];
            psum[k] += (pf[k].x + pf[k].y) + (pf[k].z + pf[k].w);
            pssq[k]  = fmaf(pf[k].x, pf[k].x, fmaf(pf[k].y, pf[k].y,
                       fmaf(pf[k].z, pf[k].z, fmaf(pf[k].w, pf[k].w, pssq[k]))));
        }
        __syncthreads();
        if (mb + MCH < CM) {
            #pragma unroll
            for (int k = 0; k < 8; ++k)
                pf[k] = *(const float4*)(xr + (size_t)(sg + (k << 5)) * SROW + (mb + MCH) + (sc << 2));
        }
        #pragma unroll
        for (int mm = 0; mm < MCH; mm += 4) {
            const float4 x0 = *(const float4*)&xt[(lane      ) * XPAD + mm];
            const float4 x1 = *(const float4*)&xt[(lane +  64) * XPAD + mm];
            const float4 x2 = *(const float4*)&xt[(lane + 128) * XPAD + mm];
            const float4 x3 = *(const float4*)&xt[(lane + 192) * XPAD + mm];
            const float* wr = wt_g + (((mb + mm) << 5) + cw);   // wave-uniform -> scalar loads
            #pragma unroll
            for (int kk = 0; kk < 4; ++kk) {
                float wv[8];
                #pragma unroll
                for (int c = 0; c < 8; ++c) wv[c] = wr[(kk << 5) + c];
                const float a0 = (kk == 0) ? x0.x : (kk == 1) ? x0.y : (kk == 2) ? x0.z : x0.w;
                const float a1 = (kk == 0) ? x1.x : (kk == 1) ? x1.y : (kk == 2) ? x1.z : x1.w;
                const float a2 = (kk == 0) ? x2.x : (kk == 1) ? x2.y : (kk == 2) ? x2.z : x2.w;
                const float a3 = (kk == 0) ? x3.x : (kk == 1) ? x3.y : (kk == 2) ? x3.z : x3.w;
                #pragma unroll
                for (int c = 0; c < 8; ++c) {
                    G[0][c] = fmaf(a0, wv[c], G[0][c]);
                    G[1][c] = fmaf(a1, wv[c], G[1][c]);
                    G[2][c] = fmaf(a2, wv[c], G[2][c]);
                    G[3][c] = fmaf(a3, wv[c], G[3][c]);
                }
            }
        }
    }

    // ---- stats: reduce over the 8 c-lanes, publish per-row mu/rstd ----
    #pragma unroll
    for (int k = 0; k < 8; ++k) {
        float s1 = psum[k], s2 = pssq[k];
        s1 += __shfl_xor(s1, 1); s1 += __shfl_xor(s1, 2); s1 += __shfl_xor(s1, 4);
        s2 += __shfl_xor(s2, 1); s2 += __shfl_xor(s2, 2); s2 += __shfl_xor(s2, 4);
        if (sc == 0) {
            const float mu  = s1 * (1.f / CM);
            const float var = s2 * (1.f / CM) - mu * mu;
            mu_s[sg + (k << 5)] = mu;
            rs_s[sg + (k << 5)] = 1.f / sqrtf(var + EPS);
        }
    }
    __syncthreads();   // all xt chunk reads done + stats visible

    // ---------------- P2: finalize a -> xt[s][32], XOR-swizzled slots ----------------
    {
        float k1v[8], k2v[8];
        #pragma unroll
        for (int c = 0; c < 8; ++c) { k1v[c] = k12[cw + c]; k2v[c] = k12[CC + cw + c]; }
        #pragma unroll
        for (int j = 0; j < 4; ++j) {
            const int s = lane + (j << 6);
            const float mu = mu_s[s], rstd = rs_s[s];
            float av[8];
            #pragma unroll
            for (int c = 0; c < 8; ++c)
                av[c] = fmaf(rstd, G[j][c] - mu * k1v[c], k2v[c]);
            const int sw = s & 7;
            *(float4*)&xt[s * CC + ((((wave << 1)    ) ^ sw) << 2)] =
                make_float4(av[0], av[1], av[2], av[3]);
            *(float4*)&xt[s * CC + ((((wave << 1) | 1) ^ sw) << 2)] =
                make_float4(av[4], av[5], av[6], av[7]);
        }
    }
    __syncthreads();

    // ---------------- P3: o = A^T A / NSEQ, split-K(4) x 4x4 tiles ----------------
    const int grp = wave;              // s-slice 64*grp .. +63
    const int xs  = (tid >> 3) & 7;    // row f4-slot
    const int ys  = tid & 7;           // col f4-slot
    float4 pr0 = {0,0,0,0}, pr1 = {0,0,0,0}, pr2 = {0,0,0,0}, pr3 = {0,0,0,0};
    #pragma unroll 4
    for (int si = 0; si < 64; ++si) {
        const int s  = (grp << 6) + si;
        const int sw = si & 7;
        const float4 ax = *(const float4*)&xt[s * CC + ((xs ^ sw) << 2)];
        const float4 ay = *(const float4*)&xt[s * CC + ((ys ^ sw) << 2)];
        pr0.x = fmaf(ax.x, ay.x, pr0.x); pr0.y = fmaf(ax.x, ay.y, pr0.y);
        pr0.z = fmaf(ax.x, ay.z, pr0.z); pr0.w = fmaf(ax.x, ay.w, pr0.w);
        pr1.x = fmaf(ax.y, ay.x, pr1.x); pr1.y = fmaf(ax.y, ay.y, pr1.y);
        pr1.z = fmaf(ax.y, ay.z, pr1.z); pr1.w = fmaf(ax.y, ay.w, pr1.w);
        pr2.x = fmaf(ax.z, ay.x, pr2.x); pr2.y = fmaf(ax.z, ay.y, pr2.y);
        pr2.z = fmaf(ax.z, ay.z, pr2.z); pr2.w = fmaf(ax.z, ay.w, pr2.w);
        pr3.x = fmaf(ax.w, ay.x, pr3.x); pr3.y = fmaf(ax.w, ay.y, pr3.y);
        pr3.z = fmaf(ax.w, ay.z, pr3.z); pr3.w = fmaf(ax.w, ay.w, pr3.w);
    }
    __syncthreads();   // all a-reads done before overwriting xt with partials
    {
        float* pb = &xt[(grp << 10) + ((xs << 2) * CC) + (ys << 2)];
        *(float4*)&pb[0 * CC] = pr0;
        *(float4*)&pb[1 * CC] = pr1;
        *(float4*)&pb[2 * CC] = pr2;
        *(float4*)&pb[3 * CC] = pr3;
    }
    __syncthreads();
    {   // reduce 4 partials -> o_lds (each thread one float4)
        const float inv_s = 1.f / NSEQ;
        float4 acc = *(const float4*)&xt[(tid << 2)];
        const float4 b1 = *(const float4*)&xt[1024 + (tid << 2)];
        const float4 b2 = *(const float4*)&xt[2048 + (tid << 2)];
        const float4 b3 = *(const float4*)&xt[3072 + (tid << 2)];
        acc.x = (acc.x + b1.x + b2.x + b3.x) * inv_s;
        acc.y = (acc.y + b1.y + b2.y + b3.y) * inv_s;
        acc.z = (acc.z + b1.z + b2.z + b3.z) * inv_s;
        acc.w = (acc.w + b1.w + b2.w + b3.w) * inv_s;
        *(float4*)&o_lds[tid << 2] = acc;
    }
    __syncthreads();

    // ---------------- P4: pre[z] = o . w_out[z] + b_out[z] -> workspace ----------------
    {
        const int z    = tid & 127;
        const int half = tid >> 7;
        const float* wrow = w_out + (size_t)z * (CC * CC) + half * 512;
        const float* op   = o_lds + half * 512;
        float po = 0.f;
        #pragma unroll 8
        for (int k = 0; k < 512; k += 4) {
            const float4 o4 = *(const float4*)&op[k];
            const float4 w4 = *(const float4*)&wrow[k];
            po = fmaf(o4.x, w4.x, fmaf(o4.y, w4.y, fmaf(o4.z, w4.z, fmaf(o4.w, w4.w, po))));
        }
        pre_part[half * CZ + z] = po;
    }
    __syncthreads();
    if (tid < CZ)
        pre_out[(size_t)r * CZ + tid] = pre_part[tid] + pre_part[CZ + tid] + b_out[tid];
}

// ===================== Kernel B: broadcast pre over 1024 rows =====================
__launch_bounds__(256, 8)
__global__ void opm_bcast(const float* __restrict__ pre,
                          float* __restrict__ out)
{
    const int bid = blockIdx.x;
    const int r   = bid >> 3;                 // 0..1023
    const int jb  = bid & 7;                  // 128-row slab within the r-plane
    const int z4  = threadIdx.x & 31;         // which float4 of the 128-float row
    const int jo  = threadIdx.x >> 5;         // 0..7

    const f4v pv = *((const f4v*)(pre + (size_t)r * CZ) + z4);
    f4v* outp = (f4v*)out + ((size_t)r * NRES + (size_t)jb * 128) * (CZ / 4);
    for (int j0 = 0; j0 < 128; j0 += 8)
        __builtin_nontemporal_store(pv, &outp[(size_t)(j0 + jo) * (CZ / 4) + z4]);
}

extern "C" void kernel_launch(void* const* d_in, const int* in_sizes, int n_in,
                              void* d_out, int out_size, void* d_ws, size_t ws_size,
                              hipStream_t stream) {
    const float* msa   = (const float*)d_in[0];
    const float* nw    = (const float*)d_in[1];
    const float* nb    = (const float*)d_in[2];
    const float* w_ab  = (const float*)d_in[3];
    const float* b_ab  = (const float*)d_in[4];
    const float* w_out = (const float*)d_in[5];
    const float* b_out = (const float*)d_in[6];
    float* out = (float*)d_out;

    float* pre  = (float*)d_ws;                    // 512 KB
    float* wt_g = pre + (size_t)NRES * CZ;         // 32 KB
    float* k12  = wt_g + CM * CC;                  // 256 B

    opm_setup<<<1, 256, 0, stream>>>(nw, nb, w_ab, b_ab, wt_g, k12);
    opm_compute<<<NRES, 256, 0, stream>>>(msa, wt_g, k12, w_out, b_out, pre);
    opm_bcast<<<NRES * 8, 256, 0, stream>>>(pre, out);
}

// Round 3
// 795.357 us; speedup vs baseline: 1.0337x; 1.0337x over previous
//
#include <hip/hip_runtime.h>

#define NSEQ 256
#define NRES 1024
#define CM   256
#define CC   32
#define CZ   128
#define EPS  1e-5f
#define SROW (NRES * CM)   // stride between s-rows of x for fixed r
#define MCH  16            // m-chunk size (floats)
#define XPAD 20            // padded row stride for x chunk: 20*i mod 32 distinct for i..i+7

typedef float f4v __attribute__((ext_vector_type(4)));

// ===================== Kernel S: precompute wt[m][c], K1, K2 =====================
// wt[m][c] = nw[m] * w_ab[c][m]; K1[c] = sum_m wt[m][c];
// K2[c] = sum_m nb[m]*w_ab[c][m] + b_ab[c].   k12 = [K1 | K2].
__global__ void opm_setup(const float* __restrict__ nw,
                          const float* __restrict__ nb,
                          const float* __restrict__ w_ab,
                          const float* __restrict__ b_ab,
                          float* __restrict__ wt_g,
                          float* __restrict__ k12)
{
    __shared__ float wls[CM * CC];
    const int t = threadIdx.x;          // 256 threads, t == m
    const float nwm = nw[t];
    #pragma unroll
    for (int c = 0; c < CC; ++c)
        wls[t * CC + c] = nwm * w_ab[c * CM + t];
    __syncthreads();
    for (int i = t; i < CM * CC; i += 256) wt_g[i] = wls[i];
    if (t < CC) {
        float k1 = 0.f, k2 = 0.f;
        for (int m = 0; m < CM; ++m) {
            k1 += wls[m * CC + t];
            k2 = fmaf(nb[m], w_ab[t * CM + m], k2);
        }
        k12[t]      = k1;
        k12[CC + t] = k2 + b_ab[t];
    }
}

// ===================== Kernel A: compute pre[r][z] =====================
// One block per residue r. 256 threads = 4 waves, 3 blocks/CU (52 KB LDS).
// LDS plan:
//   wt[8192]  32 KB : wt[m][c] during G; reused as a[s][c] (XOR-swizzled) after.
//   xt[5120]  20 KB : x chunk [s][XPAD] during G (conflict-free: row stride 20);
//                     then mu (xt[0..255]) / rstd (xt[256..511]);
//                     then o partials (xt[0..4095]) -> o (xt[0..1023]);
//                     then pre_part (xt[4096..4351]).
// G-phase identities (round-1 proven, bank-conflict-free):
//   staging: sc4=tid&3 (f4 slot), sg4=tid>>2, rows sg4+64k; stats from regs.
//   compute: sc8=tid&7 (c0=4*sc8), sg8=tid>>3, rows sg8+32j; 8 lanes broadcast
//            one row (8 distinct rows tile all 32 banks), wt broadcast by c0.
__launch_bounds__(256, 3)
__global__ void opm_compute(const float* __restrict__ msa,
                            const float* __restrict__ wt_g,
                            const float* __restrict__ k12,
                            const float* __restrict__ w_out,
                            const float* __restrict__ b_out,
                            float* __restrict__ pre_out)
{
    __shared__ float wt[CM * CC];        // 32 KB
    __shared__ float xt[NSEQ * XPAD];    // 20 KB

    const int tid  = threadIdx.x;
    const int r    = blockIdx.x;
    const int wave = tid >> 6;

    // staging identity
    const int sc4 = tid & 3;
    const int sg4 = tid >> 2;               // 0..63
    // compute identity
    const int sc8 = tid & 7;
    const int sg8 = tid >> 3;               // 0..31
    const int c0  = sc8 << 2;

    const float* xr = msa + (size_t)r * CM;

    // prologue: prefetch chunk 0 (4 lanes cover 64B contiguous per row)
    float4 pf[4];
    #pragma unroll
    for (int k = 0; k < 4; ++k)
        pf[k] = *(const float4*)(xr + (size_t)(sg4 + (k << 6)) * SROW + (sc4 << 2));

    // stage wt[m][c] from global (overlaps with prefetch; visible at chunk-0 sync2)
    #pragma unroll
    for (int k = 0; k < 8; ++k) {
        const int i = (tid + (k << 8)) << 2;
        *(float4*)&wt[i] = *(const float4*)&wt_g[i];
    }

    float G[8][4];
    #pragma unroll
    for (int j = 0; j < 8; ++j) {
        G[j][0] = 0.f; G[j][1] = 0.f; G[j][2] = 0.f; G[j][3] = 0.f;
    }
    float psum[4], pssq[4];
    #pragma unroll
    for (int k = 0; k < 4; ++k) { psum[k] = 0.f; pssq[k] = 0.f; }

    for (int mb = 0; mb < CM; mb += MCH) {
        __syncthreads();   // previous chunk's readers done
        #pragma unroll
        for (int k = 0; k < 4; ++k) {
            *(float4*)&xt[(sg4 + (k << 6)) * XPAD + (sc4 << 2)] = pf[k];
            psum[k] += (pf[k].x + pf[k].y) + (pf[k].z + pf[k].w);
            pssq[k]  = fmaf(pf[k].x, pf[k].x, fmaf(pf[k].y, pf[k].y,
                       fmaf(pf[k].z, pf[k].z, fmaf(pf[k].w, pf[k].w, pssq[k]))));
        }
        __syncthreads();   // chunk (and, first time, wt) visible
        if (mb + MCH < CM) {
            #pragma unroll
            for (int k = 0; k < 4; ++k)
                pf[k] = *(const float4*)(xr + (size_t)(sg4 + (k << 6)) * SROW + (mb + MCH) + (sc4 << 2));
        }
        #pragma unroll
        for (int mm = 0; mm < MCH; mm += 4) {
            const float4 w0 = *(const float4*)&wt[(mb + mm + 0) * CC + c0];
            const float4 w1 = *(const float4*)&wt[(mb + mm + 1) * CC + c0];
            const float4 w2 = *(const float4*)&wt[(mb + mm + 2) * CC + c0];
            const float4 w3 = *(const float4*)&wt[(mb + mm + 3) * CC + c0];
            #pragma unroll
            for (int j = 0; j < 8; ++j) {
                const float4 x4 = *(const float4*)&xt[(sg8 + (j << 5)) * XPAD + mm];
                G[j][0] = fmaf(x4.x, w0.x, fmaf(x4.y, w1.x, fmaf(x4.z, w2.x, fmaf(x4.w, w3.x, G[j][0]))));
                G[j][1] = fmaf(x4.x, w0.y, fmaf(x4.y, w1.y, fmaf(x4.z, w2.y, fmaf(x4.w, w3.y, G[j][1]))));
                G[j][2] = fmaf(x4.x, w0.z, fmaf(x4.y, w1.z, fmaf(x4.z, w2.z, fmaf(x4.w, w3.z, G[j][2]))));
                G[j][3] = fmaf(x4.x, w0.w, fmaf(x4.y, w1.w, fmaf(x4.z, w2.w, fmaf(x4.w, w3.w, G[j][3]))));
            }
        }
    }
    __syncthreads();   // (A) all chunk reads + wt reads done

    // ---- stats: reduce over the 4 sc4-lanes, publish mu/rstd into xt[0..511] ----
    #pragma unroll
    for (int k = 0; k < 4; ++k) {
        float s1 = psum[k], s2 = pssq[k];
        s1 += __shfl_xor(s1, 1); s1 += __shfl_xor(s1, 2);
        s2 += __shfl_xor(s2, 1); s2 += __shfl_xor(s2, 2);
        if (sc4 == 0) {
            const int s = sg4 + (k << 6);
            const float mu  = s1 * (1.f / CM);
            const float var = s2 * (1.f / CM) - mu * mu;
            xt[s]        = mu;
            xt[NSEQ + s] = 1.f / sqrtf(var + EPS);
        }
    }
    __syncthreads();   // (B) mu/rstd visible

    // ---------------- P2: finalize a -> wt region, XOR-swizzled f4 slots ----------------
    {
        const float4 k1v = *(const float4*)&k12[c0];
        const float4 k2v = *(const float4*)&k12[CC + c0];
        #pragma unroll
        for (int j = 0; j < 8; ++j) {
            const int s = sg8 + (j << 5);
            const float mu = xt[s], rstd = xt[NSEQ + s];
            float4 av;
            av.x = fmaf(rstd, G[j][0] - mu * k1v.x, k2v.x);
            av.y = fmaf(rstd, G[j][1] - mu * k1v.y, k2v.y);
            av.z = fmaf(rstd, G[j][2] - mu * k1v.z, k2v.z);
            av.w = fmaf(rstd, G[j][3] - mu * k1v.w, k2v.w);
            *(float4*)&wt[s * CC + ((sc8 ^ (s & 7)) << 2)] = av;
        }
    }
    __syncthreads();   // (C) a complete (mu reads done; partials may overwrite xt)

    // ---------------- P3: o = A^T A / NSEQ, split-K(4) x 4x4 tiles ----------------
    const int grp = wave;              // s-slice 64*grp .. +63
    const int xs  = (tid >> 3) & 7;    // row f4-slot
    const int ys  = tid & 7;           // col f4-slot
    float4 pr0 = {0,0,0,0}, pr1 = {0,0,0,0}, pr2 = {0,0,0,0}, pr3 = {0,0,0,0};
    #pragma unroll 4
    for (int si = 0; si < 64; ++si) {
        const int s  = (grp << 6) + si;
        const int sw = si & 7;
        const float4 ax = *(const float4*)&wt[s * CC + ((xs ^ sw) << 2)];
        const float4 ay = *(const float4*)&wt[s * CC + ((ys ^ sw) << 2)];
        pr0.x = fmaf(ax.x, ay.x, pr0.x); pr0.y = fmaf(ax.x, ay.y, pr0.y);
        pr0.z = fmaf(ax.x, ay.z, pr0.z); pr0.w = fmaf(ax.x, ay.w, pr0.w);
        pr1.x = fmaf(ax.y, ay.x, pr1.x); pr1.y = fmaf(ax.y, ay.y, pr1.y);
        pr1.z = fmaf(ax.y, ay.z, pr1.z); pr1.w = fmaf(ax.y, ay.w, pr1.w);
        pr2.x = fmaf(ax.z, ay.x, pr2.x); pr2.y = fmaf(ax.z, ay.y, pr2.y);
        pr2.z = fmaf(ax.z, ay.z, pr2.z); pr2.w = fmaf(ax.z, ay.w, pr2.w);
        pr3.x = fmaf(ax.w, ay.x, pr3.x); pr3.y = fmaf(ax.w, ay.y, pr3.y);
        pr3.z = fmaf(ax.w, ay.z, pr3.z); pr3.w = fmaf(ax.w, ay.w, pr3.w);
    }
    {   // partials into xt[grp*1024 ...] (a lives in wt region -> no extra barrier)
        float* pb = &xt[(grp << 10) + (xs << 7) + (ys << 2)];
        *(float4*)&pb[0 << 5] = pr0;
        *(float4*)&pb[1 << 5] = pr1;
        *(float4*)&pb[2 << 5] = pr2;
        *(float4*)&pb[3 << 5] = pr3;
    }
    __syncthreads();   // (D) partials visible
    {   // reduce 4 partials -> o at xt[0..1023] (same-thread overwrite of grp0)
        const float inv_s = 1.f / NSEQ;
        float4 acc = *(const float4*)&xt[(tid << 2)];
        const float4 b1 = *(const float4*)&xt[1024 + (tid << 2)];
        const float4 b2 = *(const float4*)&xt[2048 + (tid << 2)];
        const float4 b3 = *(const float4*)&xt[3072 + (tid << 2)];
        acc.x = (acc.x + b1.x + b2.x + b3.x) * inv_s;
        acc.y = (acc.y + b1.y + b2.y + b3.y) * inv_s;
        acc.z = (acc.z + b1.z + b2.z + b3.z) * inv_s;
        acc.w = (acc.w + b1.w + b2.w + b3.w) * inv_s;
        *(float4*)&xt[tid << 2] = acc;
    }
    __syncthreads();   // (E) o visible

    // ---------------- P4: pre[z] = o . w_out[z] + b_out[z] ----------------
    {
        const int z    = tid & 127;
        const int half = tid >> 7;
        const float* wrow = w_out + (size_t)z * (CC * CC) + half * 512;
        const float* op   = &xt[half * 512];
        float po = 0.f;
        #pragma unroll 8
        for (int k = 0; k < 512; k += 4) {
            const float4 o4 = *(const float4*)&op[k];
            const float4 w4 = *(const float4*)&wrow[k];
            po = fmaf(o4.x, w4.x, fmaf(o4.y, w4.y, fmaf(o4.z, w4.z, fmaf(o4.w, w4.w, po))));
        }
        xt[4096 + (half << 7) + z] = po;
    }
    __syncthreads();   // (F)
    if (tid < CZ)
        pre_out[(size_t)r * CZ + tid] = xt[4096 + tid] + xt[4096 + CZ + tid] + b_out[tid];
}

// ===================== Kernel B: broadcast pre over 1024 rows =====================
__launch_bounds__(256, 8)
__global__ void opm_bcast(const float* __restrict__ pre,
                          float* __restrict__ out)
{
    const int bid = blockIdx.x;
    const int r   = bid >> 3;                 // 0..1023
    const int jb  = bid & 7;                  // 128-row slab within the r-plane
    const int z4  = threadIdx.x & 31;         // which float4 of the 128-float row
    const int jo  = threadIdx.x >> 5;         // 0..7

    const f4v pv = *((const f4v*)(pre + (size_t)r * CZ) + z4);
    f4v* outp = (f4v*)out + ((size_t)r * NRES + (size_t)jb * 128) * (CZ / 4);
    for (int j0 = 0; j0 < 128; j0 += 8)
        __builtin_nontemporal_store(pv, &outp[(size_t)(j0 + jo) * (CZ / 4) + z4]);
}

extern "C" void kernel_launch(void* const* d_in, const int* in_sizes, int n_in,
                              void* d_out, int out_size, void* d_ws, size_t ws_size,
                              hipStream_t stream) {
    const float* msa   = (const float*)d_in[0];
    const float* nw    = (const float*)d_in[1];
    const float* nb    = (const float*)d_in[2];
    const float* w_ab  = (const float*)d_in[3];
    const float* b_ab  = (const float*)d_in[4];
    const float* w_out = (const float*)d_in[5];
    const float* b_out = (const float*)d_in[6];
    float* out = (float*)d_out;

    float* pre  = (float*)d_ws;                    // 512 KB
    float* wt_g = pre + (size_t)NRES * CZ;         // 32 KB
    float* k12  = wt_g + CM * CC;                  // 256 B

    opm_setup<<<1, 256, 0, stream>>>(nw, nb, w_ab, b_ab, wt_g, k12);
    opm_compute<<<NRES, 256, 0, stream>>>(msa, wt_g, k12, w_out, b_out, pre);
    opm_bcast<<<NRES * 8, 256, 0, stream>>>(pre, out);
}